// Round 1
// baseline (267.174 us; speedup 1.0000x reference)
//
#include <hip/hip_runtime.h>

typedef unsigned short u16;
typedef __bf16 bf16x8 __attribute__((ext_vector_type(8)));
typedef float f32x4 __attribute__((ext_vector_type(4)));

// Problem constants (from reference)
#define NB 16      // batches
#define NC 64      // channels
#define NK 207     // nodes (K_DIM)
#define NL 64      // time (L_DIM)
#define KP 224     // padded GEMM K-dim over nodes (207 -> 224 = 7*32)
#define NKL 13248  // NK*NL
#define GROWS 1152 // stacked-G rows: 5*208 + 112 pad
#define CIN 320

__device__ __forceinline__ u16 f2bf(float f) {
  unsigned u = __builtin_bit_cast(unsigned, f);
  u += 0x7FFFu + ((u >> 16) & 1u);   // RNE; inputs are never NaN
  return (u16)(u >> 16);
}

// async global->LDS, 16 B per lane. ldst must be (wave-uniform base + lane*16).
__device__ __forceinline__ void g2l16(const u16* gsrc, u16* ldst) {
  __builtin_amdgcn_global_load_lds(
      (const __attribute__((address_space(1))) unsigned int*)gsrc,
      (__attribute__((address_space(3))) unsigned int*)ldst, 16, 0, 0);
}

#define XPAD 225   // odd fp32 stride: conflict-free column access

// ---- merged prep: one kernel, branch by block range (wave-uniform) ---------
// [0,1024)   : x (B,C,K*L) fp32 -> xT[b][(l*64+c)][k] bf16 (k-padded 224)
// [1024,1280): A -> Abf rows, AbfT cols (m0..m0+31), G q=1,3
// [1280,1312): G q=0 identity
// [1312,1328): G rows 1040..1151 zero
// [1328,1344): AbfT rows 224..255 zero
// 1344       : W -> bf16
__global__ __launch_bounds__(256) void k_prep_all(
    const float* __restrict__ x, const float* __restrict__ a0,
    const float* __restrict__ a1, const float* __restrict__ W,
    u16* __restrict__ xT, u16* __restrict__ Abf, u16* __restrict__ AbfT,
    u16* __restrict__ G, u16* __restrict__ Wbf) {
  __shared__ float lds[64 * XPAD];
  int id = blockIdx.x, t = threadIdx.x;
  if (id < 1024) {
    int c = id & 63, b = id >> 6;
    const float4* xp4 = (const float4*)(x + (size_t)(b * 64 + c) * NKL);
    for (int i4 = t; i4 < 3312; i4 += 256) {   // NKL/4; 4 consecutive l, same k
      float4 v = xp4[i4];
      int k = i4 >> 4, l0 = (i4 & 15) * 4;
      lds[(l0 + 0) * XPAD + k] = v.x;
      lds[(l0 + 1) * XPAD + k] = v.y;
      lds[(l0 + 2) * XPAD + k] = v.z;
      lds[(l0 + 3) * XPAD + k] = v.w;
    }
    __syncthreads();
    for (int ch = t; ch < 64 * 28; ch += 256) {
      int l = ch / 28, kc = ch - l * 28;
      u16 v[8] __attribute__((aligned(16)));
      for (int j = 0; j < 8; j++) {
        int k = kc * 8 + j;
        v[j] = (k < NK) ? f2bf(lds[l * XPAD + k]) : (u16)0;
      }
      *(int4*)(xT + ((size_t)b * 4096 + l * 64 + c) * KP + kc * 8) = *(int4*)v;
    }
  } else if (id < 1280) {
    int local = id - 1024;
    int rt = local & 7, w = (local >> 3) & 1, b = local >> 4;
    const float* A = (w ? a1 : a0) + (size_t)b * NK * NK;
    int m0 = rt * 32;
    for (int idx = t; idx < 32 * 224; idx += 256) {
      int r = idx / 224, k = idx - r * 224;
      int m = m0 + r;
      lds[r * XPAD + k] = (m < NK && k < NK) ? A[m * NK + k] : 0.f;
    }
    __syncthreads();
    for (int ch = t; ch < 32 * 28; ch += 256) {  // row-major: Abf + G q=1,3
      int rr = ch / 28, kc = ch - rr * 28;
      u16 v[8] __attribute__((aligned(16)));
      for (int j = 0; j < 8; j++) v[j] = f2bf(lds[rr * XPAD + kc * 8 + j]);
      int m = m0 + rr;
      *(int4*)(Abf + (((size_t)b * 2 + w) * 256 + m) * KP + kc * 8) = *(int4*)v;
      if (m < 208)
        *(int4*)(G + ((size_t)b * GROWS + (1 + 2 * w) * 208 + m) * KP + kc * 8) = *(int4*)v;
    }
    if (rt < 7) {                                // transpose: AbfT[n][m0+..]
      for (int ch = t; ch < 224 * 4; ch += 256) {
        int n = ch >> 2, mc = ch & 3;
        u16 v[8] __attribute__((aligned(16)));
        for (int j = 0; j < 8; j++) v[j] = f2bf(lds[(mc * 8 + j) * XPAD + n]);
        *(int4*)(AbfT + (((size_t)b * 2 + w) * 256 + n) * KP + m0 + mc * 8) = *(int4*)v;
      }
    }
  } else if (id < 1312) {
    int local = id - 1280, b = local >> 1, half = local & 1;
    for (int ci = t; ci < 104 * 28; ci += 256) {
      int jr = ci / 28, kc = ci - jr * 28;
      int j = half * 104 + jr;
      u16 v[8] __attribute__((aligned(16)));
      for (int jj = 0; jj < 8; jj++)
        v[jj] = (j == kc * 8 + jj && j < NK) ? (u16)0x3F80 : (u16)0;
      *(int4*)(G + ((size_t)b * GROWS + j) * KP + kc * 8) = *(int4*)v;
    }
  } else if (id < 1328) {
    int b = id - 1312;
    int4 z = {0, 0, 0, 0};
    int4* p = (int4*)(G + (size_t)b * GROWS * KP + (size_t)1040 * KP);
    for (int ci = t; ci < 3136; ci += 256) p[ci] = z;
  } else if (id < 1344) {
    int b = id - 1328;
    int4 z = {0, 0, 0, 0};
    for (int ci = t; ci < 1792; ci += 256) {
      int w = ci / 896, rem = ci - w * 896;
      *(int4*)(AbfT + (((size_t)b * 2 + w) * 256 + 224) * KP + rem * 8) = z;
    }
  } else {
    for (int ci = t; ci < 2560; ci += 256) {
      u16 v[8] __attribute__((aligned(16)));
      for (int j = 0; j < 8; j++) v[j] = f2bf(W[ci * 8 + j]);
      *(int4*)(Wbf + ci * 8) = *(int4*)v;
    }
  }
}

// ---- prep: A^2 via MFMA -> G blocks q=2,4 ----------------------------------
__global__ void k_asq(const u16* __restrict__ Abf, const u16* __restrict__ AbfT,
                      u16* __restrict__ G) {
  // grid (4 ntile, 4 mtile, 32=b*2+w), 256 threads, waves 2x2, wave tile 32x32
  int b = blockIdx.z >> 1, w = blockIdx.z & 1;
  int lane = threadIdx.x & 63, wave = threadIdx.x >> 6;
  int wm = wave >> 1, wn = wave & 1;
  const u16* Ab = Abf + ((size_t)b * 2 + w) * 256 * KP;
  const u16* At = AbfT + ((size_t)b * 2 + w) * 256 * KP;
  int m0 = blockIdx.y * 64 + wm * 32;
  int n0 = blockIdx.x * 64 + wn * 32;
  int r = lane & 15, q = lane >> 4;
  f32x4 acc[2][2] = {};
  for (int k0 = 0; k0 < KP; k0 += 32) {
    bf16x8 af[2], bg[2];
    for (int i = 0; i < 2; i++)
      af[i] = *(const bf16x8*)(Ab + (size_t)(m0 + i * 16 + r) * KP + k0 + q * 8);
    for (int i = 0; i < 2; i++)
      bg[i] = *(const bf16x8*)(At + (size_t)(n0 + i * 16 + r) * KP + k0 + q * 8);
    for (int i = 0; i < 2; i++)
      for (int j = 0; j < 2; j++)
        acc[i][j] = __builtin_amdgcn_mfma_f32_16x16x32_bf16(af[i], bg[j], acc[i][j], 0, 0, 0);
  }
  int qblk = 2 + 2 * w;
  for (int i = 0; i < 2; i++)
    for (int j = 0; j < 2; j++)
      for (int rr = 0; rr < 4; rr++) {
        int mj = m0 + i * 16 + q * 4 + rr;
        int nk = n0 + j * 16 + r;
        if (mj < 208 && nk < KP)
          G[((size_t)b * GROWS + qblk * 208 + mj) * KP + nk] = f2bf(acc[i][j][rr]);
      }
}

// ---- fused diffuse+conv ----------------------------------------------------
// One block = (batch b, j-tile of 16 nodes, l-tile of 8). 512 threads, 8 waves.
// GEMM-1 (per p=0..4): T_p[j, (t,c)] = sum_k G_p[j,k] * xT[(lt*8+t)*64+c, k]
//   A-op = xT rows (m=(t,c), 512 rows), B-op = G rows (n=j, 16), K=224.
//   Lane holds (n=j fixed, 4 consecutive c) -> b64 write into LDS T[p][j][t][c].
// GEMM-2: y[o, (j,t)] = sum_{p,c} W[o, p*64+c] * T_p[j][t][c] + bias[o]
//   A-op = W rows (global, L2-hot), B-op = T rows (LDS, c-contiguous b128).
// LDS (u16 units): G tiles [0,17920) | A-stage [17920,26112) | T [26112,72192)
#define AOFF 17920
#define TOFF 26112
__global__ __launch_bounds__(512) void k_fused(
    const u16* __restrict__ G, const u16* __restrict__ xT,
    const u16* __restrict__ Wbf, const float* __restrict__ bias,
    float* __restrict__ y) {
  __shared__ __align__(16) u16 lds[72192];  // 144,384 B
  // XCD swizzle decode: consecutive blockIdx -> same l-tile (xcd), j varies,
  // so the 13 j-blocks sharing an xT slice cluster on one XCD's L2.
  int i = blockIdx.x;
  int lt = i & 7, k2 = i >> 3;
  int jt = k2 % 13, b = k2 / 13;
  int tid = threadIdx.x, wave = tid >> 6, lane = tid & 63;
  int r = lane & 15, q = lane >> 4;
  const u16* Gb = G + (size_t)b * GROWS * KP;
  const u16* Xb = xT + ((size_t)b * 4096 + lt * 512) * KP;

  // stage G: 35 fragment-major tiles (p*7+ks), 512 u16 each, loaded once
  for (int i2 = 0; i2 < 5; i2++) {
    int tile = i2 * 8 + wave;            // wave-uniform
    if (tile < 35) {
      int p = tile / 7, ks = tile - p * 7;
      g2l16(Gb + (size_t)(p * 208 + jt * 16 + r) * KP + ks * 32 + q * 8,
            &lds[tile * 512 + lane * 8]);
    }
  }

  // GEMM-1: two m-chunks of 256 xT rows; acc[5][2] per thread (40 f32)
  for (int mc = 0; mc < 2; mc++) {
    f32x4 acc1[5][2] = {};
    for (int ks = 0; ks < 7; ks++) {
      for (int i2 = 0; i2 < 2; i2++) {
        int tile = i2 * 8 + wave;        // wave-uniform
        g2l16(Xb + (size_t)(mc * 256 + tile * 16 + r) * KP + ks * 32 + q * 8,
              &lds[AOFF + tile * 512 + lane * 8]);
      }
      __syncthreads();
      bf16x8 af0 = *(const bf16x8*)&lds[AOFF + (wave * 2 + 0) * 512 + lane * 8];
      bf16x8 af1 = *(const bf16x8*)&lds[AOFF + (wave * 2 + 1) * 512 + lane * 8];
#pragma unroll
      for (int p = 0; p < 5; p++) {
        bf16x8 bg = *(const bf16x8*)&lds[(p * 7 + ks) * 512 + lane * 8];
        acc1[p][0] = __builtin_amdgcn_mfma_f32_16x16x32_bf16(af0, bg, acc1[p][0], 0, 0, 0);
        acc1[p][1] = __builtin_amdgcn_mfma_f32_16x16x32_bf16(af1, bg, acc1[p][1], 0, 0, 0);
      }
      __syncthreads();
    }
    // write T[p][j=r][t][c]: stride 72 u16 keeps rows 16B-aligned; c XOR-swizzle
    // by (j&7)<<3 spreads the j-strided write/read across banks (bijective per row).
#pragma unroll
    for (int p = 0; p < 5; p++)
#pragma unroll
      for (int mf = 0; mf < 2; mf++) {
        int m = mc * 256 + (wave * 2 + mf) * 16 + q * 4;
        int t = m >> 6, c = m & 63;
        int cs = c ^ ((r & 7) << 3);
        int idx = TOFF + ((p * 16 + r) * 8 + t) * 72 + cs;
        u16 v0 = f2bf(acc1[p][mf][0]), v1 = f2bf(acc1[p][mf][1]);
        u16 v2 = f2bf(acc1[p][mf][2]), v3 = f2bf(acc1[p][mf][3]);
        *(uint2*)&lds[idx] = make_uint2((unsigned)v0 | ((unsigned)v1 << 16),
                                        (unsigned)v2 | ((unsigned)v3 << 16));
      }
  }
  __syncthreads();

  // GEMM-2: y tile 64(o) x 128(j,t), K=320=(p,c). Wave: mo=wave>>1 o-frag,
  // nh=(wave&1)*4 n-frag half. No barriers -> compiler free to pipeline.
  int mo = wave >> 1, nh = (wave & 1) * 4;
  const u16* Wrow = Wbf + (size_t)(mo * 16 + r) * CIN + q * 8;
  f32x4 acc2[4] = {};
#pragma unroll
  for (int ks = 0; ks < 10; ks++) {
    bf16x8 aw = *(const bf16x8*)(Wrow + ks * 32);
    int p = ks >> 1, c0 = (ks & 1) * 32;
#pragma unroll
    for (int nf = 0; nf < 4; nf++) {
      int n = (nh + nf) * 16 + r;
      int j = n >> 3, t = n & 7;
      int cs = (c0 + q * 8) ^ ((j & 7) << 3);
      bf16x8 bt = *(const bf16x8*)&lds[TOFF + ((p * 16 + j) * 8 + t) * 72 + cs];
      acc2[nf] = __builtin_amdgcn_mfma_f32_16x16x32_bf16(aw, bt, acc2[nf], 0, 0, 0);
    }
  }

  // epilogue: lane r spans (j,t) with t fast -> 32B contiguous runs per 8 lanes
  int o0 = mo * 16 + q * 4;
  float4 bv = *(const float4*)&bias[o0];
  float* yb = y + (size_t)b * 64 * NKL;
#pragma unroll
  for (int nf = 0; nf < 4; nf++) {
    int n = (nh + nf) * 16 + r;
    int j = n >> 3, t = n & 7;
    int jnode = jt * 16 + j;
    if (jnode < NK) {
      int col = jnode * 64 + lt * 8 + t;
      yb[(size_t)(o0 + 0) * NKL + col] = acc2[nf][0] + bv.x;
      yb[(size_t)(o0 + 1) * NKL + col] = acc2[nf][1] + bv.y;
      yb[(size_t)(o0 + 2) * NKL + col] = acc2[nf][2] + bv.z;
      yb[(size_t)(o0 + 3) * NKL + col] = acc2[nf][3] + bv.w;
    }
  }
}

extern "C" void kernel_launch(void* const* d_in, const int* in_sizes, int n_in,
                              void* d_out, int out_size, void* d_ws, size_t ws_size,
                              hipStream_t stream) {
  const float* x = (const float*)d_in[0];
  const float* a0 = (const float*)d_in[1];
  const float* a1 = (const float*)d_in[2];
  const float* W = (const float*)d_in[3];
  const float* bias = (const float*)d_in[4];
  float* y = (float*)d_out;
  char* ws = (char*)d_ws;

  size_t off = 0;
  auto alloc = [&](size_t bytes) {
    size_t o = off;
    off = (off + bytes + 511) & ~(size_t)511;
    return o;
  };
  size_t o_xT  = alloc((size_t)NB * 4096 * KP * 2);
  size_t o_G   = alloc((size_t)NB * GROWS * KP * 2);
  size_t o_Ab  = alloc((size_t)NB * 2 * 256 * KP * 2);
  size_t o_At  = alloc((size_t)NB * 2 * 256 * KP * 2);
  size_t o_Wb  = alloc((size_t)64 * CIN * 2);
  (void)ws_size;

  u16* xT  = (u16*)(ws + o_xT);
  u16* G   = (u16*)(ws + o_G);
  u16* Abf = (u16*)(ws + o_Ab);
  u16* AbfT= (u16*)(ws + o_At);
  u16* Wbf = (u16*)(ws + o_Wb);

  k_prep_all<<<dim3(1345), 256, 0, stream>>>(x, a0, a1, W, xT, Abf, AbfT, G, Wbf);
  k_asq<<<dim3(4, 4, 32), 256, 0, stream>>>(Abf, AbfT, G);
  k_fused<<<dim3(16 * 13 * 8), 512, 0, stream>>>(G, xT, Wbf, bias, y);
}

// Round 2
// 223.404 us; speedup vs baseline: 1.1959x; 1.1959x over previous
//
#include <hip/hip_runtime.h>

typedef unsigned short u16;
typedef __bf16 bf16x8 __attribute__((ext_vector_type(8)));
typedef float f32x4 __attribute__((ext_vector_type(4)));

// Problem constants (from reference)
#define NB 16      // batches
#define NC 64      // channels
#define NK 207     // nodes (K_DIM)
#define NL 64      // time (L_DIM)
#define KP 224     // padded GEMM K-dim over nodes (207 -> 224 = 7*32)
#define NKL 13248  // NK*NL
#define GROWS 1152 // stacked-G rows: 5*208 + 112 pad
#define CIN 320

__device__ __forceinline__ u16 f2bf(float f) {
  unsigned u = __builtin_bit_cast(unsigned, f);
  u += 0x7FFFu + ((u >> 16) & 1u);   // RNE; inputs are never NaN
  return (u16)(u >> 16);
}

// async global->LDS, 16 B per lane. ldst must be (wave-uniform base + lane*16).
__device__ __forceinline__ void g2l16(const u16* gsrc, u16* ldst) {
  __builtin_amdgcn_global_load_lds(
      (const __attribute__((address_space(1))) unsigned int*)gsrc,
      (__attribute__((address_space(3))) unsigned int*)ldst, 16, 0, 0);
}

#define XPAD 225   // odd fp32 stride: conflict-free column access

// ---- merged prep: one kernel, branch by block range (wave-uniform) ---------
__global__ __launch_bounds__(256) void k_prep_all(
    const float* __restrict__ x, const float* __restrict__ a0,
    const float* __restrict__ a1, const float* __restrict__ W,
    u16* __restrict__ xT, u16* __restrict__ Abf, u16* __restrict__ AbfT,
    u16* __restrict__ G, u16* __restrict__ Wbf) {
  __shared__ float lds[64 * XPAD];
  int id = blockIdx.x, t = threadIdx.x;
  if (id < 1024) {
    int c = id & 63, b = id >> 6;
    const float4* xp4 = (const float4*)(x + (size_t)(b * 64 + c) * NKL);
    for (int i4 = t; i4 < 3312; i4 += 256) {   // NKL/4; 4 consecutive l, same k
      float4 v = xp4[i4];
      int k = i4 >> 4, l0 = (i4 & 15) * 4;
      lds[(l0 + 0) * XPAD + k] = v.x;
      lds[(l0 + 1) * XPAD + k] = v.y;
      lds[(l0 + 2) * XPAD + k] = v.z;
      lds[(l0 + 3) * XPAD + k] = v.w;
    }
    __syncthreads();
    for (int ch = t; ch < 64 * 28; ch += 256) {
      int l = ch / 28, kc = ch - l * 28;
      u16 v[8] __attribute__((aligned(16)));
      for (int j = 0; j < 8; j++) {
        int k = kc * 8 + j;
        v[j] = (k < NK) ? f2bf(lds[l * XPAD + k]) : (u16)0;
      }
      *(int4*)(xT + ((size_t)b * 4096 + l * 64 + c) * KP + kc * 8) = *(int4*)v;
    }
  } else if (id < 1280) {
    int local = id - 1024;
    int rt = local & 7, w = (local >> 3) & 1, b = local >> 4;
    const float* A = (w ? a1 : a0) + (size_t)b * NK * NK;
    int m0 = rt * 32;
    for (int idx = t; idx < 32 * 224; idx += 256) {
      int r = idx / 224, k = idx - r * 224;
      int m = m0 + r;
      lds[r * XPAD + k] = (m < NK && k < NK) ? A[m * NK + k] : 0.f;
    }
    __syncthreads();
    for (int ch = t; ch < 32 * 28; ch += 256) {  // row-major: Abf + G q=1,3
      int rr = ch / 28, kc = ch - rr * 28;
      u16 v[8] __attribute__((aligned(16)));
      for (int j = 0; j < 8; j++) v[j] = f2bf(lds[rr * XPAD + kc * 8 + j]);
      int m = m0 + rr;
      *(int4*)(Abf + (((size_t)b * 2 + w) * 256 + m) * KP + kc * 8) = *(int4*)v;
      if (m < 208)
        *(int4*)(G + ((size_t)b * GROWS + (1 + 2 * w) * 208 + m) * KP + kc * 8) = *(int4*)v;
    }
    if (rt < 7) {                                // transpose: AbfT[n][m0+..]
      for (int ch = t; ch < 224 * 4; ch += 256) {
        int n = ch >> 2, mc = ch & 3;
        u16 v[8] __attribute__((aligned(16)));
        for (int j = 0; j < 8; j++) v[j] = f2bf(lds[(mc * 8 + j) * XPAD + n]);
        *(int4*)(AbfT + (((size_t)b * 2 + w) * 256 + n) * KP + m0 + mc * 8) = *(int4*)v;
      }
    }
  } else if (id < 1312) {
    int local = id - 1280, b = local >> 1, half = local & 1;
    for (int ci = t; ci < 104 * 28; ci += 256) {
      int jr = ci / 28, kc = ci - jr * 28;
      int j = half * 104 + jr;
      u16 v[8] __attribute__((aligned(16)));
      for (int jj = 0; jj < 8; jj++)
        v[jj] = (j == kc * 8 + jj && j < NK) ? (u16)0x3F80 : (u16)0;
      *(int4*)(G + ((size_t)b * GROWS + j) * KP + kc * 8) = *(int4*)v;
    }
  } else if (id < 1328) {
    int b = id - 1312;
    int4 z = {0, 0, 0, 0};
    int4* p = (int4*)(G + (size_t)b * GROWS * KP + (size_t)1040 * KP);
    for (int ci = t; ci < 3136; ci += 256) p[ci] = z;
  } else if (id < 1344) {
    int b = id - 1328;
    int4 z = {0, 0, 0, 0};
    for (int ci = t; ci < 1792; ci += 256) {
      int w = ci / 896, rem = ci - w * 896;
      *(int4*)(AbfT + (((size_t)b * 2 + w) * 256 + 224) * KP + rem * 8) = z;
    }
  } else {
    for (int ci = t; ci < 2560; ci += 256) {
      u16 v[8] __attribute__((aligned(16)));
      for (int j = 0; j < 8; j++) v[j] = f2bf(W[ci * 8 + j]);
      *(int4*)(Wbf + ci * 8) = *(int4*)v;
    }
  }
}

// ---- prep: A^2 via MFMA -> G blocks q=2,4 ----------------------------------
__global__ void k_asq(const u16* __restrict__ Abf, const u16* __restrict__ AbfT,
                      u16* __restrict__ G) {
  int b = blockIdx.z >> 1, w = blockIdx.z & 1;
  int lane = threadIdx.x & 63, wave = threadIdx.x >> 6;
  int wm = wave >> 1, wn = wave & 1;
  const u16* Ab = Abf + ((size_t)b * 2 + w) * 256 * KP;
  const u16* At = AbfT + ((size_t)b * 2 + w) * 256 * KP;
  int m0 = blockIdx.y * 64 + wm * 32;
  int n0 = blockIdx.x * 64 + wn * 32;
  int r = lane & 15, q = lane >> 4;
  f32x4 acc[2][2] = {};
  for (int k0 = 0; k0 < KP; k0 += 32) {
    bf16x8 af[2], bg[2];
    for (int i = 0; i < 2; i++)
      af[i] = *(const bf16x8*)(Ab + (size_t)(m0 + i * 16 + r) * KP + k0 + q * 8);
    for (int i = 0; i < 2; i++)
      bg[i] = *(const bf16x8*)(At + (size_t)(n0 + i * 16 + r) * KP + k0 + q * 8);
    for (int i = 0; i < 2; i++)
      for (int j = 0; j < 2; j++)
        acc[i][j] = __builtin_amdgcn_mfma_f32_16x16x32_bf16(af[i], bg[j], acc[i][j], 0, 0, 0);
  }
  int qblk = 2 + 2 * w;
  for (int i = 0; i < 2; i++)
    for (int j = 0; j < 2; j++)
      for (int rr = 0; rr < 4; rr++) {
        int mj = m0 + i * 16 + q * 4 + rr;
        int nk = n0 + j * 16 + r;
        if (mj < 208 && nk < KP)
          G[((size_t)b * GROWS + qblk * 208 + mj) * KP + nk] = f2bf(acc[i][j][rr]);
      }
}

// ---- fused diffuse+conv, v2: 2 blocks/CU, barrier-free wave-private pipe ---
// Block = (b, jt of 16 nodes, lt of 4 l). 512 threads, 8 waves.
// GEMM-1: T_p[j,(t,c)] = sum_k G_p[j,k]*xT[(lt*4+t)*64+c, k]; M=256 rows,
//   wave-private A tiles (wave stages & reads only its own 2), double-buffered
//   with counted vmcnt(2) -> NO barriers in the K-loop. G staged once (35 KB).
// T (46 KB) aliases the phase-1 region after one __syncthreads().
// GEMM-2: y[o,(j,t)] = W @ T^T; W rows from global (L2-hot), T from LDS.
#define AG 17920            // A-stage base (u16); G region is [0, 17920)
__global__ __launch_bounds__(512, 4) void k_fused(
    const u16* __restrict__ G, const u16* __restrict__ xT,
    const u16* __restrict__ Wbf, const float* __restrict__ bias,
    float* __restrict__ y) {
  __shared__ __align__(16) u16 lds[AG + 2 * 8192];  // 68,608 B -> 2 blocks/CU
  // bijective XCD swizzle: 3328 blocks, 416/XCD = 2 batches worth, so xT
  // (13 jt share a slice) and y-lines (4 lt share a 64B line) stay in one L2.
  int id = blockIdx.x;
  int wg = (id & 7) * 416 + (id >> 3);
  int b = wg / 208, rem = wg % 208;
  int jt = rem >> 4, lt = rem & 15;
  int tid = threadIdx.x, wave = tid >> 6, lane = tid & 63;
  int r = lane & 15, q = lane >> 4;
  const u16* Gb = G + (size_t)b * GROWS * KP;
  const u16* Xb = xT + ((size_t)b * 4096 + lt * 256) * KP;

  // stage G: 35 fragment-major tiles (p*7+ks), 512 u16 each, loaded once
  for (int i2 = 0; i2 < 5; i2++) {
    int tile = i2 * 8 + wave;            // wave-uniform
    if (tile < 35) {
      int p = tile / 7, ks = tile - p * 7;
      g2l16(Gb + (size_t)(p * 208 + jt * 16 + r) * KP + ks * 32 + q * 8,
            &lds[tile * 512 + lane * 8]);
    }
  }
  // prologue: stage ks=0 into buf0 (wave-private tiles wave*2+{0,1})
  for (int i2 = 0; i2 < 2; i2++) {
    int tile = wave * 2 + i2;
    g2l16(Xb + (size_t)(tile * 16 + r) * KP + q * 8,
          &lds[AG + tile * 512 + lane * 8]);
  }
  asm volatile("s_waitcnt vmcnt(2)" ::: "memory");  // G landed; stage0 in flight
  __builtin_amdgcn_s_barrier();                     // G visible to all waves

  f32x4 acc1[5][2] = {};
#pragma unroll
  for (int ks = 0; ks < 7; ks++) {
    int cur = ks & 1;
    if (ks < 6) {                      // stage ks+1 into other buffer
      for (int i2 = 0; i2 < 2; i2++) {
        int tile = wave * 2 + i2;
        g2l16(Xb + (size_t)(tile * 16 + r) * KP + (ks + 1) * 32 + q * 8,
              &lds[AG + (cur ^ 1) * 8192 + tile * 512 + lane * 8]);
      }
      asm volatile("s_waitcnt vmcnt(2)" ::: "memory");  // buf[cur] ready (mine)
    } else {
      asm volatile("s_waitcnt vmcnt(0)" ::: "memory");
    }
    bf16x8 af0 = *(const bf16x8*)&lds[AG + cur * 8192 + (wave * 2 + 0) * 512 + lane * 8];
    bf16x8 af1 = *(const bf16x8*)&lds[AG + cur * 8192 + (wave * 2 + 1) * 512 + lane * 8];
    __builtin_amdgcn_s_setprio(1);
#pragma unroll
    for (int p = 0; p < 5; p++) {
      bf16x8 bg = *(const bf16x8*)&lds[(p * 7 + ks) * 512 + lane * 8];
      acc1[p][0] = __builtin_amdgcn_mfma_f32_16x16x32_bf16(af0, bg, acc1[p][0], 0, 0, 0);
      acc1[p][1] = __builtin_amdgcn_mfma_f32_16x16x32_bf16(af1, bg, acc1[p][1], 0, 0, 0);
    }
    __builtin_amdgcn_s_setprio(0);
  }
  __syncthreads();   // all waves done with G + A-stage; reuse LDS for T

  // write T[p][j][t][c] (stride 72 u16, 16B-aligned rows; c XOR-swizzle by j)
#pragma unroll
  for (int p = 0; p < 5; p++)
#pragma unroll
    for (int mf = 0; mf < 2; mf++) {
      int m = (wave * 2 + mf) * 16 + q * 4;
      int t = m >> 6, c = m & 63;
      int cs = c ^ ((r & 7) << 3);
      int idxT = ((p * 16 + r) * 4 + t) * 72 + cs;
      u16 v0 = f2bf(acc1[p][mf][0]), v1 = f2bf(acc1[p][mf][1]);
      u16 v2 = f2bf(acc1[p][mf][2]), v3 = f2bf(acc1[p][mf][3]);
      *(uint2*)&lds[idxT] = make_uint2((unsigned)v0 | ((unsigned)v1 << 16),
                                       (unsigned)v2 | ((unsigned)v3 << 16));
    }
  __syncthreads();

  // GEMM-2: y tile 64(o) x 64(j,t), K=320=(p,c). No barriers.
  int mo = wave >> 1, nh = (wave & 1) * 2;
  const u16* Wrow = Wbf + (size_t)(mo * 16 + r) * CIN + q * 8;
  f32x4 acc2[2] = {};
#pragma unroll
  for (int ks = 0; ks < 10; ks++) {
    bf16x8 aw = *(const bf16x8*)(Wrow + ks * 32);
    int p = ks >> 1, c0 = (ks & 1) * 32;
#pragma unroll
    for (int nf = 0; nf < 2; nf++) {
      int n = (nh + nf) * 16 + r;
      int j = n >> 2, t = n & 3;
      int cs = (c0 + q * 8) ^ ((j & 7) << 3);
      bf16x8 bt = *(const bf16x8*)&lds[((p * 16 + j) * 4 + t) * 72 + cs];
      acc2[nf] = __builtin_amdgcn_mfma_f32_16x16x32_bf16(aw, bt, acc2[nf], 0, 0, 0);
    }
  }

  // epilogue: per (o, j) the 4 t-values are 16B-contiguous in y
  int o0 = mo * 16 + q * 4;
  float4 bv = *(const float4*)&bias[o0];
  float* yb = y + (size_t)b * 64 * NKL;
#pragma unroll
  for (int nf = 0; nf < 2; nf++) {
    int n = (nh + nf) * 16 + r;
    int j = n >> 2, t = n & 3;
    int jnode = jt * 16 + j;
    if (jnode < NK) {
      int col = jnode * 64 + lt * 4 + t;
      yb[(size_t)(o0 + 0) * NKL + col] = acc2[nf][0] + bv.x;
      yb[(size_t)(o0 + 1) * NKL + col] = acc2[nf][1] + bv.y;
      yb[(size_t)(o0 + 2) * NKL + col] = acc2[nf][2] + bv.z;
      yb[(size_t)(o0 + 3) * NKL + col] = acc2[nf][3] + bv.w;
    }
  }
}

extern "C" void kernel_launch(void* const* d_in, const int* in_sizes, int n_in,
                              void* d_out, int out_size, void* d_ws, size_t ws_size,
                              hipStream_t stream) {
  const float* x = (const float*)d_in[0];
  const float* a0 = (const float*)d_in[1];
  const float* a1 = (const float*)d_in[2];
  const float* W = (const float*)d_in[3];
  const float* bias = (const float*)d_in[4];
  float* y = (float*)d_out;
  char* ws = (char*)d_ws;

  size_t off = 0;
  auto alloc = [&](size_t bytes) {
    size_t o = off;
    off = (off + bytes + 511) & ~(size_t)511;
    return o;
  };
  size_t o_xT  = alloc((size_t)NB * 4096 * KP * 2);
  size_t o_G   = alloc((size_t)NB * GROWS * KP * 2);
  size_t o_Ab  = alloc((size_t)NB * 2 * 256 * KP * 2);
  size_t o_At  = alloc((size_t)NB * 2 * 256 * KP * 2);
  size_t o_Wb  = alloc((size_t)64 * CIN * 2);
  (void)ws_size;

  u16* xT  = (u16*)(ws + o_xT);
  u16* G   = (u16*)(ws + o_G);
  u16* Abf = (u16*)(ws + o_Ab);
  u16* AbfT= (u16*)(ws + o_At);
  u16* Wbf = (u16*)(ws + o_Wb);

  k_prep_all<<<dim3(1345), 256, 0, stream>>>(x, a0, a1, W, xT, Abf, AbfT, G, Wbf);
  k_asq<<<dim3(4, 4, 32), 256, 0, stream>>>(Abf, AbfT, G);
  k_fused<<<dim3(16 * 13 * 16), 512, 0, stream>>>(G, xT, Wbf, bias, y);
}